// Round 10
// baseline (367.599 us; speedup 1.0000x reference)
//
#include <hip/hip_runtime.h>
#include <hip/hip_bf16.h>
#include <stdint.h>

#define NNODES 50000
#define NEDGES 800000
#define CH     256
#define NCLS   64
#define DCAP   64     // per-node edge capacity (P(deg>64) ~ 1e-13 for this dataset)

typedef __attribute__((ext_vector_type(8))) short  short8;
typedef __attribute__((ext_vector_type(4))) float  floatx4;

__device__ __forceinline__ float bf2f(unsigned short u) {
    union { unsigned int i; float f; } v; v.i = ((unsigned int)u) << 16; return v.f;
}
__device__ __forceinline__ unsigned short f2bf(float f) {
    union { float f; unsigned int i; } v; v.f = f;
    unsigned int x = v.i;
    return (unsigned short)((x + 0x7fffu + ((x >> 16) & 1u)) >> 16);  // RNE
}

// async 16B global -> LDS (DMA; vmcnt-tracked, drained by __syncthreads)
__device__ __forceinline__ void gl_lds16(const void* g, void* l) {
    __builtin_amdgcn_global_load_lds(
        (const __attribute__((address_space(1))) unsigned int*)g,
        (__attribute__((address_space(3))) unsigned int*)l, 16, 0, 0);
}

// --- fused setup: weights transpose + x->bf16 + cnt zero + el1/er1 zero ---
__global__ void k_setup(const float* __restrict__ W0, const float* __restrict__ W1,
                        const float* __restrict__ Wl, const float* __restrict__ x,
                        unsigned short* __restrict__ w0t, unsigned short* __restrict__ w1t,
                        unsigned short* __restrict__ wlt, unsigned short* __restrict__ xbf,
                        int* __restrict__ cnt, float* __restrict__ el1,
                        float* __restrict__ er1) {
    int i = blockIdx.x * 256 + threadIdx.x;
    if (i < 65536) {
        int r = i >> 8, c = i & 255;
        w0t[c * 256 + r] = f2bf(W0[i]);
    } else if (i < 131072) {
        int j = i - 65536;
        int r = j >> 8, c = j & 255;
        w1t[c * 256 + r] = f2bf(W1[j]);
    } else if (i < 147456) {
        int j = i - 131072;
        int r = j >> 6, c = j & 63;       // Wl is [256,64]
        wlt[c * 256 + r] = f2bf(Wl[j]);
    } else if (i < 147456 + NNODES) {
        cnt[i - 147456] = 0;
    } else if (i < 147456 + NNODES + NNODES * CH / 8) {
        int j = i - (147456 + NNODES);    // 8-elem chunk of x
        const float4* xp = (const float4*)(x + (size_t)j * 8);
        float4 v0 = xp[0], v1 = xp[1];
        ushort4 o0, o1;
        o0.x = f2bf(v0.x); o0.y = f2bf(v0.y); o0.z = f2bf(v0.z); o0.w = f2bf(v0.w);
        o1.x = f2bf(v1.x); o1.y = f2bf(v1.y); o1.z = f2bf(v1.z); o1.w = f2bf(v1.w);
        *(ushort4*)(xbf + (size_t)j * 8)     = o0;
        *(ushort4*)(xbf + (size_t)j * 8 + 4) = o1;
    } else {
        int j2 = i - (147456 + NNODES + NNODES * CH / 8);
        if (j2 < NNODES) el1[j2] = 0.f;
        else if (j2 < 2 * NNODES) er1[j2 - NNODES] = 0.f;
    }
}

// ------- one-pass bucket-CSR: append src into fixed-stride slots of dst -------
__global__ void k_scatter(const int* __restrict__ dst, const int* __restrict__ src,
                          int* __restrict__ cnt, int* __restrict__ esrc) {
    int e = blockIdx.x * 256 + threadIdx.x;
    if (e < NEDGES) {
        int d = dst[e];
        if ((unsigned)d < NNODES) {
            int p = atomicAdd(&cnt[d], 1);
            if (p < DCAP) esrc[(size_t)d * DCAP + p] = src[e];
        }
    }
}

// ------------- weight-stationary GEMM, column-split for 2 blocks/CU -------------
// Block = 512 thr (8 waves), covers columns [n0, n0+BN) of 7*16*G2 rows.
// Stage B-half into LDS (XOR-swizzled rows via pre-swizzled source), ONE barrier,
// then per-wave reg-resident MFMA with zero further barriers.
// HEL>0: fused el/er. If BN < CH/HEL (head spans halves): partial via atomicAdd.
template<int BN, int G2, bool AF32, bool OUTF32, int HEL>
__global__ __launch_bounds__(512, 2) void k_gemmw2(
        const void* __restrict__ Av, const unsigned short* __restrict__ BT,
        const float* __restrict__ bias,
        float* __restrict__ Cf, unsigned short* __restrict__ Cb,
        int M, int N,
        const float* __restrict__ al, const float* __restrict__ ar,
        float* __restrict__ el, float* __restrict__ er) {
    constexpr int NT     = BN / 16;
    constexpr int RBT    = 7 * 16 * G2;
    constexpr int ROUNDS = BN / 16;               // gl_lds16 per thread
    __shared__ unsigned short Bw[BN * 256];       // 64 KB (BN=128) / 32 KB (BN=64)
    const int t  = threadIdx.x;
    const int w  = t >> 6, l = t & 63;
    const int lm = l & 15, lg = l >> 4;
    const int n0 = blockIdx.y * BN;

    // ---- stage B-half: linear LDS dst, inverse-swizzled global src ----
    const char* Bsrc = (const char*)BT + (size_t)n0 * 512;
#pragma unroll
    for (int r = 0; r < ROUNDS; ++r) {
        int g    = r * 8192 + t * 16;             // linear dst byte
        int lrow = g >> 9;
        int bir  = g & 511;
        int sb   = (g & ~511) | (bir ^ ((lrow & 7) << 4));
        gl_lds16(Bsrc + sb, (char*)Bw + r * 8192 + w * 1024);
    }

    const int m0    = blockIdx.x * RBT;
    const int tile0 = m0 + w * 16 * G2;
    const bool active = (w < 7) && (tile0 < M);

    // ---- A fragments: direct global->reg, issued before the barrier ----
    const unsigned short* Ab = (const unsigned short*)Av;
    const float*          Af = (const float*)Av;
    short8 af[G2][8];
#pragma unroll
    for (int g2 = 0; g2 < G2; ++g2) {
        int arow = tile0 + g2 * 16 + lm;
        bool ok = active && (arow < M);
#pragma unroll
        for (int ks = 0; ks < 8; ++ks) {
            if (AF32) {
                short8 v = (short8)0;
                if (ok) {
                    const float* ap = Af + (size_t)arow * 256 + ks * 32 + lg * 8;
                    float4 v0 = *(const float4*)(ap), v1 = *(const float4*)(ap + 4);
                    v[0] = (short)f2bf(v0.x); v[1] = (short)f2bf(v0.y);
                    v[2] = (short)f2bf(v0.z); v[3] = (short)f2bf(v0.w);
                    v[4] = (short)f2bf(v1.x); v[5] = (short)f2bf(v1.y);
                    v[6] = (short)f2bf(v1.z); v[7] = (short)f2bf(v1.w);
                }
                af[g2][ks] = v;
            } else {
                af[g2][ks] = ok ? *(const short8*)(Ab + (size_t)arow * 256 + ks * 32 + lg * 8)
                                : (short8)0;
            }
        }
    }

    __syncthreads();                              // drains gl_lds DMA (+ A loads)
    if (!active) return;

    // ---- MFMA: swizzled B reads from LDS ----
    floatx4 acc[G2][NT];
#pragma unroll
    for (int g2 = 0; g2 < G2; ++g2)
#pragma unroll
        for (int nt = 0; nt < NT; ++nt) acc[g2][nt] = (floatx4)0.0f;

    const int kx   = (lm >> 2) & 1;
    const int coff = (lg * 16) ^ ((lm & 3) << 4);
    const char* Bb = (const char*)Bw;
#pragma unroll
    for (int ks = 0; ks < 8; ++ks) {
        int kk = (ks ^ kx) * 64;
#pragma unroll
        for (int nt = 0; nt < NT; ++nt) {
            short8 bf = *(const short8*)(Bb + (nt * 16 + lm) * 512 + kk + coff);
#pragma unroll
            for (int g2 = 0; g2 < G2; ++g2)
                acc[g2][nt] = __builtin_amdgcn_mfma_f32_16x16x32_bf16(af[g2][ks], bf,
                                                                      acc[g2][nt], 0, 0, 0);
        }
    }

    // ---- epilogue: C write (+ fused el/er) ----
    float alv[HEL > 0 ? NT : 1], arv[HEL > 0 ? NT : 1];
    if constexpr (HEL > 0) {
#pragma unroll
        for (int nt = 0; nt < NT; ++nt) {
            alv[nt] = al[n0 + nt * 16 + lm];
            arv[nt] = ar[n0 + nt * 16 + lm];
        }
    }
#pragma unroll
    for (int g2 = 0; g2 < G2; ++g2)
#pragma unroll
        for (int j = 0; j < 4; ++j) {
            int row = tile0 + g2 * 16 + lg * 4 + j;
            if (row < M) {
#pragma unroll
                for (int nt = 0; nt < NT; ++nt) {
                    int gcol = n0 + nt * 16 + lm;
                    float v = acc[g2][nt][j];
                    if (bias) v += bias[gcol];
                    if (OUTF32) Cf[(size_t)row * N + gcol] = v;
                    else        Cb[(size_t)row * N + gcol] = f2bf(v);
                }
                if constexpr (HEL > 0) {
                    constexpr int D = CH / (HEL > 0 ? HEL : 1);
                    if constexpr (BN >= D) {       // heads aligned within this half
                        constexpr int HLOC = BN / D;
                        constexpr int NPH  = NT / HLOC;
                        int h0 = n0 / D;
#pragma unroll
                        for (int hl = 0; hl < HLOC; ++hl) {
                            float sl = 0.f, sr = 0.f;
#pragma unroll
                            for (int q = 0; q < NPH; ++q) {
                                int nt = hl * NPH + q;
                                float v = acc[g2][nt][j];
                                sl += v * alv[nt];
                                sr += v * arv[nt];
                            }
#pragma unroll
                            for (int mm = 1; mm < 16; mm <<= 1) {
                                sl += __shfl_xor(sl, mm, 64);
                                sr += __shfl_xor(sr, mm, 64);
                            }
                            if (lm == 0) {
                                el[(size_t)row * HEL + h0 + hl] = sl;
                                er[(size_t)row * HEL + h0 + hl] = sr;
                            }
                        }
                    } else {                       // head spans halves: partial sums
                        float sl = 0.f, sr = 0.f;
#pragma unroll
                        for (int nt = 0; nt < NT; ++nt) {
                            float v = acc[g2][nt][j];
                            sl += v * alv[nt];
                            sr += v * arv[nt];
                        }
#pragma unroll
                        for (int mm = 1; mm < 16; mm <<= 1) {
                            sl += __shfl_xor(sl, mm, 64);
                            sr += __shfl_xor(sr, mm, 64);
                        }
                        if (lm == 0) {
                            atomicAdd(&el[row], sl);
                            atomicAdd(&er[row], sr);
                        }
                    }
                }
            }
        }
}

// ---------------- aggregation: inline softmax weight + scalar gather-FMA ----------------
// Bucket CSR. nbase: node offset (kernel split into halves for profiling visibility).
template<int H, bool ELU, bool RESID>
__global__ __launch_bounds__(256) void k_agg5(
        const unsigned short* __restrict__ ft,
        const float* __restrict__ el, const float* __restrict__ er,
        const int* __restrict__ cnt,
        const int* __restrict__ esrc,
        const unsigned short* __restrict__ resid16,
        const float* __restrict__ bias,
        unsigned short* __restrict__ out_bf,
        float* __restrict__ out_f, int nbase) {
    int w = threadIdx.x >> 6;
    int n = nbase + blockIdx.x * 4 + w;
    int l = threadIdx.x & 63;
    int c = 4 * l;
    int st = n * DCAP;
    int dg = __builtin_amdgcn_readfirstlane(cnt[n]);
    if (dg > DCAP) dg = DCAP;
    if (dg < 0) dg = 0;
    float a0 = 0.f, a1 = 0.f, a2 = 0.f, a3 = 0.f, wsum = 0.f;
    const unsigned short* ftc = ft + c;

    if (H == 1) {
        float ern = er[n];
        for (int i = 0; i < dg; i += 64) {
            int idx = i + l;
            int sv = 0; float wv = 0.f;
            if (idx < dg) {
                sv = esrc[st + idx];
                float xv = el[sv] + ern;
                xv = (xv > 0.f) ? xv : 0.2f * xv;
                xv = fminf(xv, 60.f);
                wv = __expf(xv);
            }
            wsum += wv;
            int jmax = dg - i; if (jmax > 64) jmax = 64;
            int j = 0;
            for (; j + 4 <= jmax; j += 4) {
                int s0 = __builtin_amdgcn_readlane(sv, j + 0);
                int s1 = __builtin_amdgcn_readlane(sv, j + 1);
                int s2 = __builtin_amdgcn_readlane(sv, j + 2);
                int s3 = __builtin_amdgcn_readlane(sv, j + 3);
                float w0 = __int_as_float(__builtin_amdgcn_readlane(__float_as_int(wv), j + 0));
                float w1 = __int_as_float(__builtin_amdgcn_readlane(__float_as_int(wv), j + 1));
                float w2 = __int_as_float(__builtin_amdgcn_readlane(__float_as_int(wv), j + 2));
                float w3 = __int_as_float(__builtin_amdgcn_readlane(__float_as_int(wv), j + 3));
                ushort4 f0 = *(const ushort4*)(ftc + (size_t)s0 * CH);
                ushort4 f1 = *(const ushort4*)(ftc + (size_t)s1 * CH);
                ushort4 f2 = *(const ushort4*)(ftc + (size_t)s2 * CH);
                ushort4 f3 = *(const ushort4*)(ftc + (size_t)s3 * CH);
                a0 += w0 * bf2f(f0.x) + w1 * bf2f(f1.x) + w2 * bf2f(f2.x) + w3 * bf2f(f3.x);
                a1 += w0 * bf2f(f0.y) + w1 * bf2f(f1.y) + w2 * bf2f(f2.y) + w3 * bf2f(f3.y);
                a2 += w0 * bf2f(f0.z) + w1 * bf2f(f1.z) + w2 * bf2f(f2.z) + w3 * bf2f(f3.z);
                a3 += w0 * bf2f(f0.w) + w1 * bf2f(f1.w) + w2 * bf2f(f2.w) + w3 * bf2f(f3.w);
            }
            for (; j < jmax; ++j) {
                int s0 = __builtin_amdgcn_readlane(sv, j);
                float w0 = __int_as_float(__builtin_amdgcn_readlane(__float_as_int(wv), j));
                ushort4 f0 = *(const ushort4*)(ftc + (size_t)s0 * CH);
                a0 += w0 * bf2f(f0.x); a1 += w0 * bf2f(f0.y);
                a2 += w0 * bf2f(f0.z); a3 += w0 * bf2f(f0.w);
            }
        }
#pragma unroll
        for (int m = 1; m < 64; m <<= 1) wsum += __shfl_xor(wsum, m, 64);
    } else {
        int head = l & 3, slot = l >> 2;       // phase-1 role of this lane
        int h = l >> 4;                        // phase-2 head (c / 64)
        float ern = er[n * 4 + head];
        for (int i = 0; i < dg; i += 16) {
            int idx = i + slot;
            int sv = 0; float wv = 0.f;
            if (idx < dg) {
                sv = esrc[st + idx];
                float xv = el[sv * 4 + head] + ern;
                xv = (xv > 0.f) ? xv : 0.2f * xv;
                xv = fminf(xv, 60.f);
                wv = __expf(xv);
            }
            wsum += wv;
            int jmax = dg - i; if (jmax > 16) jmax = 16;
            int j = 0;
            for (; j + 4 <= jmax; j += 4) {
                int s0 = __builtin_amdgcn_readlane(sv, 4 * (j + 0));
                int s1 = __builtin_amdgcn_readlane(sv, 4 * (j + 1));
                int s2 = __builtin_amdgcn_readlane(sv, 4 * (j + 2));
                int s3 = __builtin_amdgcn_readlane(sv, 4 * (j + 3));
                float w0 = __shfl(wv, 4 * (j + 0) + h, 64);
                float w1 = __shfl(wv, 4 * (j + 1) + h, 64);
                float w2 = __shfl(wv, 4 * (j + 2) + h, 64);
                float w3 = __shfl(wv, 4 * (j + 3) + h, 64);
                ushort4 f0 = *(const ushort4*)(ftc + (size_t)s0 * CH);
                ushort4 f1 = *(const ushort4*)(ftc + (size_t)s1 * CH);
                ushort4 f2 = *(const ushort4*)(ftc + (size_t)s2 * CH);
                ushort4 f3 = *(const ushort4*)(ftc + (size_t)s3 * CH);
                a0 += w0 * bf2f(f0.x) + w1 * bf2f(f1.x) + w2 * bf2f(f2.x) + w3 * bf2f(f3.x);
                a1 += w0 * bf2f(f0.y) + w1 * bf2f(f1.y) + w2 * bf2f(f2.y) + w3 * bf2f(f3.y);
                a2 += w0 * bf2f(f0.z) + w1 * bf2f(f1.z) + w2 * bf2f(f2.z) + w3 * bf2f(f3.z);
                a3 += w0 * bf2f(f0.w) + w1 * bf2f(f1.w) + w2 * bf2f(f2.w) + w3 * bf2f(f3.w);
            }
            for (; j < jmax; ++j) {
                int s0 = __builtin_amdgcn_readlane(sv, 4 * j);
                float w0 = __shfl(wv, 4 * j + h, 64);
                ushort4 f0 = *(const ushort4*)(ftc + (size_t)s0 * CH);
                a0 += w0 * bf2f(f0.x); a1 += w0 * bf2f(f0.y);
                a2 += w0 * bf2f(f0.z); a3 += w0 * bf2f(f0.w);
            }
        }
#pragma unroll
        for (int m = 4; m < 64; m <<= 1) wsum += __shfl_xor(wsum, m, 64);
        wsum = __shfl(wsum, l >> 4, 64);
    }
    float inv = (wsum > 1e-30f) ? 1.0f / wsum : 0.0f;
    a0 *= inv; a1 *= inv; a2 *= inv; a3 *= inv;
    if (RESID) {
        ushort4 r = *(const ushort4*)(resid16 + (size_t)n * CH + c);
        a0 += bf2f(r.x); a1 += bf2f(r.y); a2 += bf2f(r.z); a3 += bf2f(r.w);
    }
    {
        float4 b = *(const float4*)(bias + c);
        a0 += b.x; a1 += b.y; a2 += b.z; a3 += b.w;
    }
    if (ELU) {
        a0 = (a0 > 0.f) ? a0 : __expf(a0) - 1.f;
        a1 = (a1 > 0.f) ? a1 : __expf(a1) - 1.f;
        a2 = (a2 > 0.f) ? a2 : __expf(a2) - 1.f;
        a3 = (a3 > 0.f) ? a3 : __expf(a3) - 1.f;
    }
    if (out_bf) {
        ushort4 ov; ov.x = f2bf(a0); ov.y = f2bf(a1); ov.z = f2bf(a2); ov.w = f2bf(a3);
        *(ushort4*)(out_bf + (size_t)n * CH + c) = ov;
    }
    if (out_f) {
        *(float4*)(out_f + (size_t)n * CH + c) = make_float4(a0, a1, a2, a3);
    }
}

// ---------------- launch ----------------

extern "C" void kernel_launch(void* const* d_in, const int* in_sizes, int n_in,
                              void* d_out, int out_size, void* d_ws, size_t ws_size,
                              hipStream_t stream) {
    const float* x   = (const float*)d_in[0];
    const int*   src = (const int*)d_in[1];
    const int*   dst = (const int*)d_in[2];
    const float* W0  = (const float*)d_in[3];
    const float* al0 = (const float*)d_in[4];
    const float* ar0 = (const float*)d_in[5];
    const float* b0  = (const float*)d_in[6];
    const float* W1  = (const float*)d_in[7];
    const float* al1 = (const float*)d_in[8];
    const float* ar1 = (const float*)d_in[9];
    const float* b1  = (const float*)d_in[10];
    const float* Wl  = (const float*)d_in[11];
    const float* bl  = (const float*)d_in[12];

    float* out_logits = (float*)d_out;
    float* out_h      = out_logits + (size_t)NNODES * NCLS;

    // xbf (25.6 MB) lives in the out_h region: dead after GEMM-0, long before agg<1> writes out_h
    unsigned short* xbf = (unsigned short*)out_h;

    // ws: ft 25.6 + h0bf 25.6 + esrc 12.8 + weights ~0.3 + small arrays
    char* ws = (char*)d_ws;
    size_t o = 0;
    auto alloc = [&](size_t b) { char* p = ws + o; o += (b + 255) & ~(size_t)255; return p; };
    unsigned short* ft   = (unsigned short*)alloc((size_t)NNODES * CH * 2);
    unsigned short* h0bf = (unsigned short*)alloc((size_t)NNODES * CH * 2);
    int*            esrc = (int*)alloc((size_t)NNODES * DCAP * 4);
    unsigned short* w0t  = (unsigned short*)alloc(256 * 256 * 2);
    unsigned short* w1t  = (unsigned short*)alloc(256 * 256 * 2);
    unsigned short* wlt  = (unsigned short*)alloc(64 * 256 * 2);
    int*            cnt  = (int*)alloc((size_t)NNODES * 4);
    float*          el0  = (float*)alloc((size_t)NNODES * 4 * 4);
    float*          er0  = (float*)alloc((size_t)NNODES * 4 * 4);
    float*          el1  = (float*)alloc((size_t)NNODES * 4);
    float*          er1  = (float*)alloc((size_t)NNODES * 4);

    // ---- setup (weights + xcast + cnt zero + el1/er1 zero) + one-pass bucket CSR ----
    int setup_items = 147456 + NNODES + NNODES * CH / 8 + 2 * NNODES;
    k_setup<<<(setup_items + 255) / 256, 256, 0, stream>>>(W0, W1, Wl, x,
                                                           w0t, w1t, wlt, xbf, cnt, el1, er1);
    k_scatter<<<(NEDGES + 255) / 256, 256, 0, stream>>>(dst, src, cnt, esrc);

    int gm2 = (NNODES + 223) / 224;   // 224 row-blocks (G2=2: 224 rows each)
    int gm1 = (NNODES + 111) / 112;   // 447 row-blocks (G2=1: 112 rows each)
    int ga  = (NNODES / 2) / 4;       // 6250 blocks per agg half

    // ---- layer 0 ----
    k_gemmw2<128, 2, false, false, 4><<<dim3(gm2, 2), 512, 0, stream>>>(
        xbf, w0t, nullptr, nullptr, ft, NNODES, CH, al0, ar0, el0, er0);
    k_agg5<4, true, false><<<ga, 256, 0, stream>>>(
        ft, el0, er0, cnt, esrc, nullptr, b0, h0bf, nullptr, 0);
    k_agg5<4, true, false><<<ga, 256, 0, stream>>>(
        ft, el0, er0, cnt, esrc, nullptr, b0, h0bf, nullptr, NNODES / 2);
    // ---- layer 1 (el1/er1 accumulated via atomics across column halves) ----
    k_gemmw2<128, 2, false, false, 1><<<dim3(gm2, 2), 512, 0, stream>>>(
        h0bf, w1t, nullptr, nullptr, ft, NNODES, CH, al1, ar1, el1, er1);
    k_agg5<1, false, true><<<ga, 256, 0, stream>>>(
        ft, el1, er1, cnt, esrc, h0bf, b1, nullptr, out_h, 0);
    k_agg5<1, false, true><<<ga, 256, 0, stream>>>(
        ft, el1, er1, cnt, esrc, h0bf, b1, nullptr, out_h, NNODES / 2);
    // ---- classifier (reads out_h f32) ----
    k_gemmw2<64, 1, true, true, 0><<<dim3(gm1, 1), 512, 0, stream>>>(
        out_h, wlt, bl, out_logits, nullptr, NNODES, NCLS,
        nullptr, nullptr, nullptr, nullptr);
}

// Round 11
// 335.011 us; speedup vs baseline: 1.0973x; 1.0973x over previous
//
#include <hip/hip_runtime.h>
#include <hip/hip_bf16.h>
#include <stdint.h>

#define NNODES 50000
#define NEDGES 800000
#define CH     256
#define NCLS   64
#define DCAP   64     // per-node edge capacity (P(deg>64) ~ 1e-13 for this dataset)
#define RB     224    // rows per GEMM block (7 waves x 32)
#define EPB    3572   // edges scattered per GEMM-0 block (224 * 3572 >= 800000)

typedef __attribute__((ext_vector_type(8))) short  short8;
typedef __attribute__((ext_vector_type(4))) float  floatx4;

__device__ __forceinline__ float bf2f(unsigned short u) {
    union { unsigned int i; float f; } v; v.i = ((unsigned int)u) << 16; return v.f;
}
__device__ __forceinline__ unsigned short f2bf(float f) {
    union { float f; unsigned int i; } v; v.f = f;
    unsigned int x = v.i;
    return (unsigned short)((x + 0x7fffu + ((x >> 16) & 1u)) >> 16);  // RNE
}

// async 16B global -> LDS (DMA; vmcnt-tracked, drained by __syncthreads)
__device__ __forceinline__ void gl_lds16(const void* g, void* l) {
    __builtin_amdgcn_global_load_lds(
        (const __attribute__((address_space(1))) unsigned int*)g,
        (__attribute__((address_space(3))) unsigned int*)l, 16, 0, 0);
}

// ------- fused setup: zero cnt + transpose-convert weights + x -> bf16 cast -------
__global__ void k_setup(const float* __restrict__ W0, const float* __restrict__ W1,
                        const float* __restrict__ Wl, const float* __restrict__ x,
                        unsigned short* __restrict__ w0t, unsigned short* __restrict__ w1t,
                        unsigned short* __restrict__ wlt, unsigned short* __restrict__ xbf,
                        int* __restrict__ cnt) {
    int i = blockIdx.x * 256 + threadIdx.x;
    if (i < 65536) {
        int r = i >> 8, c = i & 255;
        w0t[c * 256 + r] = f2bf(W0[i]);
    } else if (i < 131072) {
        int j = i - 65536;
        int r = j >> 8, c = j & 255;
        w1t[c * 256 + r] = f2bf(W1[j]);
    } else if (i < 147456) {
        int j = i - 131072;
        int r = j >> 6, c = j & 63;       // Wl is [256,64]
        wlt[c * 256 + r] = f2bf(Wl[j]);
    } else if (i < 147456 + NNODES) {
        cnt[i - 147456] = 0;
    } else {
        int j = i - (147456 + NNODES);    // 8-elem chunk of x
        if (j < NNODES * CH / 8) {
            const float4* xp = (const float4*)(x + (size_t)j * 8);
            float4 v0 = xp[0], v1 = xp[1];
            ushort4 o0, o1;
            o0.x = f2bf(v0.x); o0.y = f2bf(v0.y); o0.z = f2bf(v0.z); o0.w = f2bf(v0.w);
            o1.x = f2bf(v1.x); o1.y = f2bf(v1.y); o1.z = f2bf(v1.z); o1.w = f2bf(v1.w);
            *(ushort4*)(xbf + (size_t)j * 8)     = o0;
            *(ushort4*)(xbf + (size_t)j * 8 + 4) = o1;
        }
    }
}

// ---------------- weight-stationary GEMM: full B in LDS, one barrier ----------------
// 512 threads (8 waves). All waves stage B ([BN][256] bf16, XOR-swizzled via
// pre-swizzled global src) then ONE __syncthreads. Waves 0..6 each own a 32-row
// super-tile (reg-resident A, swizzled ds_read_b128 B, 0 further barriers).
// Wave 7: if SCAT, runs the bucket-CSR scatter for this block's edge slice
// (independent work hidden under the GEMM; consumer agg launches later).
template<int BN, bool AF32, bool OUTF32, int HEL, bool SCAT>
__global__ __launch_bounds__(512, 1) void k_gemmw(
        const void* __restrict__ Av, const unsigned short* __restrict__ BT,
        const float* __restrict__ bias,
        float* __restrict__ Cf, unsigned short* __restrict__ Cb,
        int M, int N,
        const float* __restrict__ al, const float* __restrict__ ar,
        float* __restrict__ el, float* __restrict__ er,
        const int* __restrict__ edst, const int* __restrict__ esr,
        int* __restrict__ cnt, int* __restrict__ esrc) {
    constexpr int NT     = BN / 16;
    constexpr int ROUNDS = (BN * 512) / 8192;     // 16 (BN=256) / 4 (BN=64)
    __shared__ unsigned short Bw[BN * 256];       // 128 KB (BN=256) / 32 KB (BN=64)
    const int t  = threadIdx.x;
    const int w  = t >> 6, l = t & 63;
    const int lm = l & 15, lg = l >> 4;

    // ---- stage all of B: linear LDS dst, inverse-swizzled global src ----
#pragma unroll
    for (int r = 0; r < ROUNDS; ++r) {
        int g   = r * 8192 + t * 16;              // linear dst byte
        int row = g >> 9;
        int bir = g & 511;
        int sb  = (g & ~511) | (bir ^ ((row & 7) << 4));
        gl_lds16((const char*)BT + sb, (char*)Bw + r * 8192 + w * 1024);
    }

    const int m0    = blockIdx.x * RB;
    const int Mb    = (m0 + RB < M) ? (m0 + RB) : M;
    const int tile0 = m0 + w * 32;
    const bool active = (w < 7) && (tile0 < Mb);

    // ---- A fragments: direct global->reg, issued before the barrier ----
    const unsigned short* Ab = (const unsigned short*)Av;
    const float*          Af = (const float*)Av;
    short8 af[2][8];
#pragma unroll
    for (int g = 0; g < 2; ++g) {
        int arow = tile0 + g * 16 + lm;
        bool ok = active && (arow < M);
#pragma unroll
        for (int ks = 0; ks < 8; ++ks) {
            if (AF32) {
                short8 v = (short8)0;
                if (ok) {
                    const float* ap = Af + (size_t)arow * 256 + ks * 32 + lg * 8;
                    float4 v0 = *(const float4*)(ap), v1 = *(const float4*)(ap + 4);
                    v[0] = (short)f2bf(v0.x); v[1] = (short)f2bf(v0.y);
                    v[2] = (short)f2bf(v0.z); v[3] = (short)f2bf(v0.w);
                    v[4] = (short)f2bf(v1.x); v[5] = (short)f2bf(v1.y);
                    v[6] = (short)f2bf(v1.z); v[7] = (short)f2bf(v1.w);
                }
                af[g][ks] = v;
            } else {
                af[g][ks] = ok ? *(const short8*)(Ab + (size_t)arow * 256 + ks * 32 + lg * 8)
                               : (short8)0;
            }
        }
    }

    __syncthreads();                              // drains gl_lds (and A loads)

    if (w == 7) {
        if (SCAT) {
            // ---- bucket-CSR scatter for this block's edge slice (4-way pipelined) ----
            int base = blockIdx.x * EPB;
            int end  = base + EPB; if (end > NEDGES) end = NEDGES;
            int e = base + l;
            for (; e + 192 < end; e += 256) {
                int d0 = edst[e],       s0 = esr[e];
                int d1 = edst[e + 64],  s1 = esr[e + 64];
                int d2 = edst[e + 128], s2 = esr[e + 128];
                int d3 = edst[e + 192], s3 = esr[e + 192];
                int p0 = ((unsigned)d0 < NNODES) ? atomicAdd(&cnt[d0], 1) : DCAP;
                int p1 = ((unsigned)d1 < NNODES) ? atomicAdd(&cnt[d1], 1) : DCAP;
                int p2 = ((unsigned)d2 < NNODES) ? atomicAdd(&cnt[d2], 1) : DCAP;
                int p3 = ((unsigned)d3 < NNODES) ? atomicAdd(&cnt[d3], 1) : DCAP;
                if (p0 < DCAP) esrc[(size_t)d0 * DCAP + p0] = s0;
                if (p1 < DCAP) esrc[(size_t)d1 * DCAP + p1] = s1;
                if (p2 < DCAP) esrc[(size_t)d2 * DCAP + p2] = s2;
                if (p3 < DCAP) esrc[(size_t)d3 * DCAP + p3] = s3;
            }
            for (; e < end; e += 64) {
                int d = edst[e];
                if ((unsigned)d < NNODES) {
                    int p = atomicAdd(&cnt[d], 1);
                    if (p < DCAP) esrc[(size_t)d * DCAP + p] = esr[e];
                }
            }
        }
        return;
    }
    if (!active) return;

    // ---- MFMA: swizzled B reads from LDS, 2 row-groups share each fragment ----
    floatx4 acc[2][NT];
#pragma unroll
    for (int g = 0; g < 2; ++g)
#pragma unroll
        for (int nt = 0; nt < NT; ++nt) acc[g][nt] = (floatx4)0.0f;

    const int kx   = (lm >> 2) & 1;
    const int coff = (lg * 16) ^ ((lm & 3) << 4);
    const char* Bb = (const char*)Bw;
#pragma unroll
    for (int ks = 0; ks < 8; ++ks) {
        int kk = (ks ^ kx) * 64;
#pragma unroll
        for (int nt = 0; nt < NT; ++nt) {
            short8 bf = *(const short8*)(Bb + (nt * 16 + lm) * 512 + kk + coff);
            acc[0][nt] = __builtin_amdgcn_mfma_f32_16x16x32_bf16(af[0][ks], bf, acc[0][nt], 0, 0, 0);
            acc[1][nt] = __builtin_amdgcn_mfma_f32_16x16x32_bf16(af[1][ks], bf, acc[1][nt], 0, 0, 0);
        }
    }

    // ---- epilogue: C write (+ fused el/er) ----
    float alv[HEL > 0 ? NT : 1], arv[HEL > 0 ? NT : 1];
    if constexpr (HEL > 0) {
#pragma unroll
        for (int nt = 0; nt < NT; ++nt) {
            alv[nt] = al[nt * 16 + lm];
            arv[nt] = ar[nt * 16 + lm];
        }
    }
#pragma unroll
    for (int g = 0; g < 2; ++g)
#pragma unroll
        for (int j = 0; j < 4; ++j) {
            int row = tile0 + g * 16 + lg * 4 + j;
            if (row < Mb) {
#pragma unroll
                for (int nt = 0; nt < NT; ++nt) {
                    int gcol = nt * 16 + lm;
                    float v = acc[g][nt][j];
                    if (bias) v += bias[gcol];
                    if (OUTF32) Cf[(size_t)row * N + gcol] = v;
                    else        Cb[(size_t)row * N + gcol] = f2bf(v);
                }
                if constexpr (HEL > 0) {
#pragma unroll
                    for (int h = 0; h < HEL; ++h) {
                        float sl = 0.f, sr = 0.f;
#pragma unroll
                        for (int q = 0; q < NT / HEL; ++q) {
                            int nt = h * (NT / HEL) + q;
                            float v = acc[g][nt][j];
                            sl += v * alv[nt];
                            sr += v * arv[nt];
                        }
#pragma unroll
                        for (int mm = 1; mm < 16; mm <<= 1) {
                            sl += __shfl_xor(sl, mm, 64);
                            sr += __shfl_xor(sr, mm, 64);
                        }
                        if (lm == 0) {
                            el[(size_t)row * HEL + h] = sl;
                            er[(size_t)row * HEL + h] = sr;
                        }
                    }
                }
            }
        }
}

// ---------------- aggregation: inline softmax weight + scalar gather-FMA ----------------
// Bucket CSR: node n's edges at esrc[n*DCAP .. n*DCAP+deg). No LDS.
template<int H, bool ELU, bool RESID>
__global__ __launch_bounds__(256) void k_agg5(
        const unsigned short* __restrict__ ft,
        const float* __restrict__ el, const float* __restrict__ er,
        const int* __restrict__ cnt,
        const int* __restrict__ esrc,
        const unsigned short* __restrict__ resid16,
        const float* __restrict__ bias,
        unsigned short* __restrict__ out_bf,
        float* __restrict__ out_f) {
    int w = threadIdx.x >> 6;
    int n = blockIdx.x * 4 + w;
    int l = threadIdx.x & 63;
    int c = 4 * l;
    int st = n * DCAP;
    int dg = __builtin_amdgcn_readfirstlane(cnt[n]);
    if (dg > DCAP) dg = DCAP;
    if (dg < 0) dg = 0;
    float a0 = 0.f, a1 = 0.f, a2 = 0.f, a3 = 0.f, wsum = 0.f;
    const unsigned short* ftc = ft + c;

    if (H == 1) {
        float ern = er[n];
        for (int i = 0; i < dg; i += 64) {
            int idx = i + l;
            int sv = 0; float wv = 0.f;
            if (idx < dg) {
                sv = esrc[st + idx];
                float xv = el[sv] + ern;
                xv = (xv > 0.f) ? xv : 0.2f * xv;
                xv = fminf(xv, 60.f);
                wv = __expf(xv);
            }
            wsum += wv;
            int jmax = dg - i; if (jmax > 64) jmax = 64;
            int j = 0;
            for (; j + 4 <= jmax; j += 4) {
                int s0 = __builtin_amdgcn_readlane(sv, j + 0);
                int s1 = __builtin_amdgcn_readlane(sv, j + 1);
                int s2 = __builtin_amdgcn_readlane(sv, j + 2);
                int s3 = __builtin_amdgcn_readlane(sv, j + 3);
                float w0 = __int_as_float(__builtin_amdgcn_readlane(__float_as_int(wv), j + 0));
                float w1 = __int_as_float(__builtin_amdgcn_readlane(__float_as_int(wv), j + 1));
                float w2 = __int_as_float(__builtin_amdgcn_readlane(__float_as_int(wv), j + 2));
                float w3 = __int_as_float(__builtin_amdgcn_readlane(__float_as_int(wv), j + 3));
                ushort4 f0 = *(const ushort4*)(ftc + (size_t)s0 * CH);
                ushort4 f1 = *(const ushort4*)(ftc + (size_t)s1 * CH);
                ushort4 f2 = *(const ushort4*)(ftc + (size_t)s2 * CH);
                ushort4 f3 = *(const ushort4*)(ftc + (size_t)s3 * CH);
                a0 += w0 * bf2f(f0.x) + w1 * bf2f(f1.x) + w2 * bf2f(f2.x) + w3 * bf2f(f3.x);
                a1 += w0 * bf2f(f0.y) + w1 * bf2f(f1.y) + w2 * bf2f(f2.y) + w3 * bf2f(f3.y);
                a2 += w0 * bf2f(f0.z) + w1 * bf2f(f1.z) + w2 * bf2f(f2.z) + w3 * bf2f(f3.z);
                a3 += w0 * bf2f(f0.w) + w1 * bf2f(f1.w) + w2 * bf2f(f2.w) + w3 * bf2f(f3.w);
            }
            for (; j < jmax; ++j) {
                int s0 = __builtin_amdgcn_readlane(sv, j);
                float w0 = __int_as_float(__builtin_amdgcn_readlane(__float_as_int(wv), j));
                ushort4 f0 = *(const ushort4*)(ftc + (size_t)s0 * CH);
                a0 += w0 * bf2f(f0.x); a1 += w0 * bf2f(f0.y);
                a2 += w0 * bf2f(f0.z); a3 += w0 * bf2f(f0.w);
            }
        }
#pragma unroll
        for (int m = 1; m < 64; m <<= 1) wsum += __shfl_xor(wsum, m, 64);
    } else {
        int head = l & 3, slot = l >> 2;       // phase-1 role of this lane
        int h = l >> 4;                        // phase-2 head (c / 64)
        float ern = er[n * 4 + head];
        for (int i = 0; i < dg; i += 16) {
            int idx = i + slot;
            int sv = 0; float wv = 0.f;
            if (idx < dg) {
                sv = esrc[st + idx];
                float xv = el[sv * 4 + head] + ern;
                xv = (xv > 0.f) ? xv : 0.2f * xv;
                xv = fminf(xv, 60.f);
                wv = __expf(xv);
            }
            wsum += wv;
            int jmax = dg - i; if (jmax > 16) jmax = 16;
            int j = 0;
            for (; j + 4 <= jmax; j += 4) {
                int s0 = __builtin_amdgcn_readlane(sv, 4 * (j + 0));
                int s1 = __builtin_amdgcn_readlane(sv, 4 * (j + 1));
                int s2 = __builtin_amdgcn_readlane(sv, 4 * (j + 2));
                int s3 = __builtin_amdgcn_readlane(sv, 4 * (j + 3));
                float w0 = __shfl(wv, 4 * (j + 0) + h, 64);
                float w1 = __shfl(wv, 4 * (j + 1) + h, 64);
                float w2 = __shfl(wv, 4 * (j + 2) + h, 64);
                float w3 = __shfl(wv, 4 * (j + 3) + h, 64);
                ushort4 f0 = *(const ushort4*)(ftc + (size_t)s0 * CH);
                ushort4 f1 = *(const ushort4*)(ftc + (size_t)s1 * CH);
                ushort4 f2 = *(const ushort4*)(ftc + (size_t)s2 * CH);
                ushort4 f3 = *(const ushort4*)(ftc + (size_t)s3 * CH);
                a0 += w0 * bf2f(f0.x) + w1 * bf2f(f1.x) + w2 * bf2f(f2.x) + w3 * bf2f(f3.x);
                a1 += w0 * bf2f(f0.y) + w1 * bf2f(f1.y) + w2 * bf2f(f2.y) + w3 * bf2f(f3.y);
                a2 += w0 * bf2f(f0.z) + w1 * bf2f(f1.z) + w2 * bf2f(f2.z) + w3 * bf2f(f3.z);
                a3 += w0 * bf2f(f0.w) + w1 * bf2f(f1.w) + w2 * bf2f(f2.w) + w3 * bf2f(f3.w);
            }
            for (; j < jmax; ++j) {
                int s0 = __builtin_amdgcn_readlane(sv, 4 * j);
                float w0 = __shfl(wv, 4 * j + h, 64);
                ushort4 f0 = *(const ushort4*)(ftc + (size_t)s0 * CH);
                a0 += w0 * bf2f(f0.x); a1 += w0 * bf2f(f0.y);
                a2 += w0 * bf2f(f0.z); a3 += w0 * bf2f(f0.w);
            }
        }
#pragma unroll
        for (int m = 4; m < 64; m <<= 1) wsum += __shfl_xor(wsum, m, 64);
        wsum = __shfl(wsum, l >> 4, 64);
    }
    float inv = (wsum > 1e-30f) ? 1.0f / wsum : 0.0f;
    a0 *= inv; a1 *= inv; a2 *= inv; a3 *= inv;
    if (RESID) {
        ushort4 r = *(const ushort4*)(resid16 + (size_t)n * CH + c);
        a0 += bf2f(r.x); a1 += bf2f(r.y); a2 += bf2f(r.z); a3 += bf2f(r.w);
    }
    {
        float4 b = *(const float4*)(bias + c);
        a0 += b.x; a1 += b.y; a2 += b.z; a3 += b.w;
    }
    if (ELU) {
        a0 = (a0 > 0.f) ? a0 : __expf(a0) - 1.f;
        a1 = (a1 > 0.f) ? a1 : __expf(a1) - 1.f;
        a2 = (a2 > 0.f) ? a2 : __expf(a2) - 1.f;
        a3 = (a3 > 0.f) ? a3 : __expf(a3) - 1.f;
    }
    if (out_bf) {
        ushort4 ov; ov.x = f2bf(a0); ov.y = f2bf(a1); ov.z = f2bf(a2); ov.w = f2bf(a3);
        *(ushort4*)(out_bf + (size_t)n * CH + c) = ov;
    }
    if (out_f) {
        *(float4*)(out_f + (size_t)n * CH + c) = make_float4(a0, a1, a2, a3);
    }
}

// ---------------- launch ----------------

extern "C" void kernel_launch(void* const* d_in, const int* in_sizes, int n_in,
                              void* d_out, int out_size, void* d_ws, size_t ws_size,
                              hipStream_t stream) {
    const float* x   = (const float*)d_in[0];
    const int*   src = (const int*)d_in[1];
    const int*   dst = (const int*)d_in[2];
    const float* W0  = (const float*)d_in[3];
    const float* al0 = (const float*)d_in[4];
    const float* ar0 = (const float*)d_in[5];
    const float* b0  = (const float*)d_in[6];
    const float* W1  = (const float*)d_in[7];
    const float* al1 = (const float*)d_in[8];
    const float* ar1 = (const float*)d_in[9];
    const float* b1  = (const float*)d_in[10];
    const float* Wl  = (const float*)d_in[11];
    const float* bl  = (const float*)d_in[12];

    float* out_logits = (float*)d_out;
    float* out_h      = out_logits + (size_t)NNODES * NCLS;

    // xbf (25.6 MB) lives in the out_h region: dead after GEMM-0, long before agg<1> writes out_h
    unsigned short* xbf = (unsigned short*)out_h;

    // ws: ft 25.6 + h0bf 25.6 + esrc 12.8 + weights ~0.3 + small arrays
    char* ws = (char*)d_ws;
    size_t o = 0;
    auto alloc = [&](size_t b) { char* p = ws + o; o += (b + 255) & ~(size_t)255; return p; };
    unsigned short* ft   = (unsigned short*)alloc((size_t)NNODES * CH * 2);
    unsigned short* h0bf = (unsigned short*)alloc((size_t)NNODES * CH * 2);
    int*            esrc = (int*)alloc((size_t)NNODES * DCAP * 4);
    unsigned short* w0t  = (unsigned short*)alloc(256 * 256 * 2);
    unsigned short* w1t  = (unsigned short*)alloc(256 * 256 * 2);
    unsigned short* wlt  = (unsigned short*)alloc(64 * 256 * 2);
    int*            cnt  = (int*)alloc((size_t)NNODES * 4);
    float*          el0  = (float*)alloc((size_t)NNODES * 4 * 4);
    float*          er0  = (float*)alloc((size_t)NNODES * 4 * 4);
    float*          el1  = (float*)alloc((size_t)NNODES * 4);
    float*          er1  = (float*)alloc((size_t)NNODES * 4);

    // ---- setup (weights + xcast + cnt zero) ----
    int setup_items = 147456 + NNODES + NNODES * CH / 8;
    k_setup<<<(setup_items + 255) / 256, 256, 0, stream>>>(W0, W1, Wl, x,
                                                           w0t, w1t, wlt, xbf, cnt);

    int gm = (NNODES + RB - 1) / RB;  // 224
    // ---- layer 0: GEMM + hidden scatter (wave 7) ----
    k_gemmw<256, false, false, 4, true><<<gm, 512, 0, stream>>>(
        xbf, w0t, nullptr, nullptr, ft, NNODES, CH, al0, ar0, el0, er0,
        dst, src, cnt, esrc);
    k_agg5<4, true, false><<<NNODES / 4, 256, 0, stream>>>(
        ft, el0, er0, cnt, esrc, nullptr, b0, h0bf, nullptr);
    // ---- layer 1 ----
    k_gemmw<256, false, false, 1, false><<<gm, 512, 0, stream>>>(
        h0bf, w1t, nullptr, nullptr, ft, NNODES, CH, al1, ar1, el1, er1,
        nullptr, nullptr, nullptr, nullptr);
    k_agg5<1, false, true><<<NNODES / 4, 256, 0, stream>>>(
        ft, el1, er1, cnt, esrc, h0bf, b1, nullptr, out_h);
    // ---- classifier (reads out_h f32) ----
    k_gemmw<64, true, true, 0, false><<<gm, 512, 0, stream>>>(
        out_h, wlt, bl, out_logits, nullptr, NNODES, NCLS,
        nullptr, nullptr, nullptr, nullptr,
        nullptr, nullptr, nullptr, nullptr);
}